// Round 1
// baseline (316.162 us; speedup 1.0000x reference)
//
#include <hip/hip_runtime.h>
#include <math.h>

#define NCONST 100
#define NF     16
#define NEDGE  9900   // 100*99

// One block per batch element. 256 threads.
// LDS: xbn (BN'd features), Pr/Ps (per-node layer-1 projections, padded to 32),
// agg (scatter target, padded to 8), plus tiny fc buffers. ~36 KB total.
__global__ __launch_bounds__(256) void convint_fused(
    const float* __restrict__ x,
    const float* __restrict__ bn_g, const float* __restrict__ bn_b,
    const float* __restrict__ bn_m, const float* __restrict__ bn_v,
    const float* __restrict__ frw1, const float* __restrict__ frb1,
    const float* __restrict__ frw2, const float* __restrict__ frb2,
    const float* __restrict__ frw3, const float* __restrict__ frb3,
    const float* __restrict__ fow1, const float* __restrict__ fob1,
    const float* __restrict__ fow2, const float* __restrict__ fob2,
    const float* __restrict__ fow3, const float* __restrict__ fob3,
    const float* __restrict__ fcw1, const float* __restrict__ fcb1,
    const float* __restrict__ fcw2, const float* __restrict__ fcb2,
    float* __restrict__ out)
{
    __shared__ float xbn[NCONST][NF];   // 6.4 KB
    __shared__ float Pr[NCONST][32];    // 12.8 KB (30 used, padded for float4)
    __shared__ float Ps[NCONST][32];    // 12.8 KB
    __shared__ float agg[NCONST][8];    // 3.2 KB (6 used)
    __shared__ float fcin[8];
    __shared__ float hfc[48];
    __shared__ float logits[8];

    const int b   = blockIdx.x;
    const int tid = threadIdx.x;
    const float* xb = x + (size_t)b * (NCONST * NF);

    // ---- BatchNorm (inference) into LDS ----
    for (int idx = tid; idx < NCONST * NF; idx += 256) {
        int f = idx & 15;
        float sc = rsqrtf(bn_v[f] + 1e-3f) * bn_g[f];
        xbn[idx >> 4][f] = (xb[idx] - bn_m[f]) * sc + bn_b[f];
    }
    for (int idx = tid; idx < NCONST * 8; idx += 256)
        ((float*)agg)[idx] = 0.f;
    if (tid < 8) fcin[tid] = 0.f;
    __syncthreads();

    // ---- Per-node layer-1 projections: Pr = xbn @ W1[0:16,:], Ps = xbn @ W1[16:32,:] ----
    // 100 nodes * 30 outputs * 2 halves = 6000 dot-16 items.
    for (int idx = tid; idx < 6000; idx += 256) {
        int n   = idx / 60;
        int rem = idx - n * 60;
        int sel = (rem >= 30) ? 1 : 0;
        int o   = rem - sel * 30;
        const float* w = frw1 + (sel * 16) * 30 + o;   // stride 30 over feature rows
        float acc = 0.f;
        #pragma unroll
        for (int f = 0; f < 16; ++f) acc = fmaf(xbn[n][f], w[f * 30], acc);
        if (sel) Ps[n][o] = acc; else Pr[n][o] = acc;
    }
    __syncthreads();

    // ---- Edge MLP + scatter-add ----
    // Enumerate e = s*100 + i : receiver i = e%100 (distinct within a wave),
    // sender j = (i+1+s)%100. Covers all ordered pairs i != j exactly once.
    for (int e = tid; e < NEDGE; e += 256) {
        int s = e / 100;
        int i = e - s * 100;
        int j = i + 1 + s;
        if (j >= 100) j -= 100;

        // h1 = relu(Pr[i] + Ps[j] + b1)   (layer-1 factorized: 30 adds, 0 MACs)
        float h1[30];
        const float4* pr4 = (const float4*)(&Pr[i][0]);
        const float4* ps4 = (const float4*)(&Ps[j][0]);
        #pragma unroll
        for (int q = 0; q < 7; ++q) {
            float4 a = pr4[q];
            float4 c = ps4[q];
            h1[4*q+0] = fmaxf(a.x + c.x + frb1[4*q+0], 0.f);
            h1[4*q+1] = fmaxf(a.y + c.y + frb1[4*q+1], 0.f);
            h1[4*q+2] = fmaxf(a.z + c.z + frb1[4*q+2], 0.f);
            h1[4*q+3] = fmaxf(a.w + c.w + frb1[4*q+3], 0.f);
        }
        h1[28] = fmaxf(Pr[i][28] + Ps[j][28] + frb1[28], 0.f);
        h1[29] = fmaxf(Pr[i][29] + Ps[j][29] + frb1[29], 0.f);

        // h2 = relu(h1 @ W2 + b2)  -- weights via wave-uniform index -> s_load
        float h2[15];
        #pragma unroll
        for (int o = 0; o < 15; ++o) h2[o] = frb2[o];
        #pragma unroll
        for (int k = 0; k < 30; ++k) {
            float hk = h1[k];
            #pragma unroll
            for (int o = 0; o < 15; ++o) h2[o] = fmaf(hk, frw2[k*15+o], h2[o]);
        }
        #pragma unroll
        for (int o = 0; o < 15; ++o) h2[o] = fmaxf(h2[o], 0.f);

        // eff = relu(h2 @ W3 + b3); scatter-add to receiver i
        #pragma unroll
        for (int c = 0; c < 6; ++c) {
            float acc = frb3[c];
            #pragma unroll
            for (int k = 0; k < 15; ++k) acc = fmaf(h2[k], frw3[k*6+c], acc);
            atomicAdd(&agg[i][c], fmaxf(acc, 0.f));
        }
    }
    __syncthreads();

    // ---- Per-node fo MLP (22 -> 45 -> 22 -> 6), then sum over nodes ----
    if (tid < NCONST) {
        float in[22];
        #pragma unroll
        for (int f = 0; f < 16; ++f) in[f] = xbn[tid][f];
        #pragma unroll
        for (int c = 0; c < 6; ++c) in[16 + c] = agg[tid][c];

        float h1[45];
        #pragma unroll
        for (int o = 0; o < 45; ++o) h1[o] = fob1[o];
        #pragma unroll
        for (int k = 0; k < 22; ++k) {
            float v = in[k];
            #pragma unroll
            for (int o = 0; o < 45; ++o) h1[o] = fmaf(v, fow1[k*45+o], h1[o]);
        }
        #pragma unroll
        for (int o = 0; o < 45; ++o) h1[o] = fmaxf(h1[o], 0.f);

        float h2[22];
        #pragma unroll
        for (int o = 0; o < 22; ++o) h2[o] = fob2[o];
        #pragma unroll
        for (int k = 0; k < 45; ++k) {
            float v = h1[k];
            #pragma unroll
            for (int o = 0; o < 22; ++o) h2[o] = fmaf(v, fow2[k*22+o], h2[o]);
        }
        #pragma unroll
        for (int o = 0; o < 22; ++o) h2[o] = fmaxf(h2[o], 0.f);

        #pragma unroll
        for (int c = 0; c < 6; ++c) {
            float acc = fob3[c];
            #pragma unroll
            for (int k = 0; k < 22; ++k) acc = fmaf(h2[k], fow3[k*6+c], acc);
            atomicAdd(&fcin[c], fmaxf(acc, 0.f));
        }
    }
    __syncthreads();

    // ---- fc: 6 -> 48 (relu) -> 5 -> softmax ----
    if (tid < 48) {
        float acc = fcb1[tid];
        #pragma unroll
        for (int k = 0; k < 6; ++k) acc = fmaf(fcin[k], fcw1[k*48 + tid], acc);
        hfc[tid] = fmaxf(acc, 0.f);
    }
    __syncthreads();
    if (tid < 5) {
        float acc = fcb2[tid];
        #pragma unroll
        for (int k = 0; k < 48; ++k) acc = fmaf(hfc[k], fcw2[k*5 + tid], acc);
        logits[tid] = acc;
    }
    __syncthreads();
    if (tid == 0) {
        float m = logits[0];
        #pragma unroll
        for (int c = 1; c < 5; ++c) m = fmaxf(m, logits[c]);
        float ex[5], sum = 0.f;
        #pragma unroll
        for (int c = 0; c < 5; ++c) { ex[c] = __expf(logits[c] - m); sum += ex[c]; }
        float inv = 1.f / sum;
        #pragma unroll
        for (int c = 0; c < 5; ++c) out[(size_t)b * 5 + c] = ex[c] * inv;
    }
}

extern "C" void kernel_launch(void* const* d_in, const int* in_sizes, int n_in,
                              void* d_out, int out_size, void* d_ws, size_t ws_size,
                              hipStream_t stream) {
    const float* x     = (const float*)d_in[0];
    const float* bn_g  = (const float*)d_in[1];
    const float* bn_b  = (const float*)d_in[2];
    const float* bn_m  = (const float*)d_in[3];
    const float* bn_v  = (const float*)d_in[4];
    const float* frw1  = (const float*)d_in[5];
    const float* frb1  = (const float*)d_in[6];
    const float* frw2  = (const float*)d_in[7];
    const float* frb2  = (const float*)d_in[8];
    const float* frw3  = (const float*)d_in[9];
    const float* frb3  = (const float*)d_in[10];
    const float* fow1  = (const float*)d_in[11];
    const float* fob1  = (const float*)d_in[12];
    const float* fow2  = (const float*)d_in[13];
    const float* fob2  = (const float*)d_in[14];
    const float* fow3  = (const float*)d_in[15];
    const float* fob3  = (const float*)d_in[16];
    const float* fcw1  = (const float*)d_in[17];
    const float* fcb1  = (const float*)d_in[18];
    const float* fcw2  = (const float*)d_in[19];
    const float* fcb2  = (const float*)d_in[20];

    const int B = in_sizes[0] / (NCONST * NF);   // 512

    convint_fused<<<dim3(B), dim3(256), 0, stream>>>(
        x, bn_g, bn_b, bn_m, bn_v,
        frw1, frb1, frw2, frb2, frw3, frb3,
        fow1, fob1, fow2, fob2, fow3, fob3,
        fcw1, fcb1, fcw2, fcb2,
        (float*)d_out);
}

// Round 2
// 276.823 us; speedup vs baseline: 1.1421x; 1.1421x over previous
//
#include <hip/hip_runtime.h>
#include <math.h>

#define NCONST 100
#define NF     16
#define NEDGE  9900   // 100*99
#define BLK    512

// One block per batch element, 512 threads (8 waves; 2 blocks/CU -> 16 waves/CU).
// Pr/Ps are XOR-swizzled on 16B slots so the edge loop's ds_read_b128 at
// lane-distinct rows is bank-conflict-free (8 consecutive rows cover 32 banks).
// agg rows padded to 9 floats (coprime to 32) so ds atomic adds don't alias.
__global__ __launch_bounds__(BLK, 4) void convint_fused(
    const float* __restrict__ x,
    const float* __restrict__ bn_g, const float* __restrict__ bn_b,
    const float* __restrict__ bn_m, const float* __restrict__ bn_v,
    const float* __restrict__ frw1, const float* __restrict__ frb1,
    const float* __restrict__ frw2, const float* __restrict__ frb2,
    const float* __restrict__ frw3, const float* __restrict__ frb3,
    const float* __restrict__ fow1, const float* __restrict__ fob1,
    const float* __restrict__ fow2, const float* __restrict__ fob2,
    const float* __restrict__ fow3, const float* __restrict__ fob3,
    const float* __restrict__ fcw1, const float* __restrict__ fcb1,
    const float* __restrict__ fcw2, const float* __restrict__ fcb2,
    float* __restrict__ out)
{
    __shared__ float xbn[NCONST][NF];    // 6.4 KB
    __shared__ float Pr[NCONST][32];     // 12.8 KB, swizzled 16B slots
    __shared__ float Ps[NCONST][32];     // 12.8 KB, swizzled
    __shared__ float agg[NCONST][9];     // 3.6 KB (6 used, 9 breaks bank stride)
    __shared__ float foh1[NCONST][46];   // 18.4 KB (45 used)
    __shared__ float foh2[NCONST][23];   // 9.2 KB (22 used)
    __shared__ float fcin[8];
    __shared__ float hfc[48];
    __shared__ float logits[8];

    const int b   = blockIdx.x;
    const int tid = threadIdx.x;
    const float* xb = x + (size_t)b * (NCONST * NF);

    // ---- BatchNorm (inference) into LDS ----
    for (int idx = tid; idx < NCONST * NF; idx += BLK) {
        int f = idx & 15;
        float sc = rsqrtf(bn_v[f] + 1e-3f) * bn_g[f];
        xbn[idx >> 4][f] = (xb[idx] - bn_m[f]) * sc + bn_b[f];
    }
    for (int idx = tid; idx < NCONST * 9; idx += BLK)
        ((float*)agg)[idx] = 0.f;
    if (tid < 8) fcin[tid] = 0.f;
    __syncthreads();

    // ---- Per-node layer-1 projections (swizzled store) ----
    // Pr = xbn @ W1[0:16,:], Ps = xbn @ W1[16:32,:]; 6000 dot-16 items.
    for (int idx = tid; idx < 6000; idx += BLK) {
        int n   = idx / 60;
        int rem = idx - n * 60;
        int sel = (rem >= 30) ? 1 : 0;
        int o   = rem - sel * 30;
        const float* w = frw1 + (sel * 16) * 30 + o;   // stride 30 over feature rows
        float acc = 0.f;
        #pragma unroll
        for (int f = 0; f < 16; ++f) acc = fmaf(xbn[n][f], w[f * 30], acc);
        int col = (((o >> 2) ^ (n & 7)) << 2) + (o & 3);   // swizzled column
        if (sel) Ps[n][col] = acc; else Pr[n][col] = acc;
    }
    __syncthreads();

    // ---- Edge MLP + scatter-add ----
    // e = s*100 + i : receiver i = e%100 (distinct across lanes), sender
    // j = (i+1+s)%100. Covers all ordered pairs i != j exactly once.
    for (int e = tid; e < NEDGE; e += BLK) {
        int s = e / 100;
        int i = e - s * 100;
        int j = i + 1 + s;
        if (j >= 100) j -= 100;

        const float4* pr4 = (const float4*)(&Pr[i][0]);
        const float4* ps4 = (const float4*)(&Ps[j][0]);
        const int mi = i & 7, mj = j & 7;

        // h1 = relu(Pr[i] + Ps[j] + b1)   (layer-1 factorized)
        float h1[30];
        #pragma unroll
        for (int q = 0; q < 7; ++q) {
            float4 a = pr4[q ^ mi];          // swizzled slot -> logical quad q
            float4 c = ps4[q ^ mj];
            h1[4*q+0] = fmaxf(a.x + c.x + frb1[4*q+0], 0.f);
            h1[4*q+1] = fmaxf(a.y + c.y + frb1[4*q+1], 0.f);
            h1[4*q+2] = fmaxf(a.z + c.z + frb1[4*q+2], 0.f);
            h1[4*q+3] = fmaxf(a.w + c.w + frb1[4*q+3], 0.f);
        }
        {
            float4 a = pr4[7 ^ mi];
            float4 c = ps4[7 ^ mj];
            h1[28] = fmaxf(a.x + c.x + frb1[28], 0.f);
            h1[29] = fmaxf(a.y + c.y + frb1[29], 0.f);
        }

        // h2 = relu(h1 @ W2 + b2)  -- weights wave-uniform -> scalar loads
        float h2[15];
        #pragma unroll
        for (int o = 0; o < 15; ++o) h2[o] = frb2[o];
        #pragma unroll
        for (int k = 0; k < 30; ++k) {
            float hk = h1[k];
            #pragma unroll
            for (int o = 0; o < 15; ++o) h2[o] = fmaf(hk, frw2[k*15+o], h2[o]);
        }
        #pragma unroll
        for (int o = 0; o < 15; ++o) h2[o] = fmaxf(h2[o], 0.f);

        // eff = relu(h2 @ W3 + b3); scatter-add to receiver i
        #pragma unroll
        for (int c = 0; c < 6; ++c) {
            float acc = frb3[c];
            #pragma unroll
            for (int k = 0; k < 15; ++k) acc = fmaf(h2[k], frw3[k*6+c], acc);
            atomicAdd(&agg[i][c], fmaxf(acc, 0.f));
        }
    }
    __syncthreads();

    // ---- fo MLP, item-parallel: layer1 (100x45 dot-22) ----
    for (int idx = tid; idx < NCONST * 45; idx += BLK) {
        int n = idx / 45, o = idx - n * 45;
        float acc = fob1[o];
        #pragma unroll
        for (int k = 0; k < 16; ++k) acc = fmaf(xbn[n][k], fow1[k*45+o], acc);
        #pragma unroll
        for (int k = 0; k < 6; ++k)  acc = fmaf(agg[n][k], fow1[(16+k)*45+o], acc);
        foh1[n][o] = fmaxf(acc, 0.f);
    }
    __syncthreads();

    // ---- fo layer2 (100x22 dot-45) ----
    for (int idx = tid; idx < NCONST * 22; idx += BLK) {
        int n = idx / 22, o = idx - n * 22;
        float acc = fob2[o];
        #pragma unroll
        for (int k = 0; k < 45; ++k) acc = fmaf(foh1[n][k], fow2[k*22+o], acc);
        foh2[n][o] = fmaxf(acc, 0.f);
    }
    __syncthreads();

    // ---- fo layer3 (100x6 dot-22) + sum over nodes ----
    for (int idx = tid; idx < NCONST * 6; idx += BLK) {
        int n = idx / 6, c = idx - n * 6;
        float acc = fob3[c];
        #pragma unroll
        for (int k = 0; k < 22; ++k) acc = fmaf(foh2[n][k], fow3[k*6+c], acc);
        atomicAdd(&fcin[c], fmaxf(acc, 0.f));
    }
    __syncthreads();

    // ---- fc: 6 -> 48 (relu) -> 5 -> softmax ----
    if (tid < 48) {
        float acc = fcb1[tid];
        #pragma unroll
        for (int k = 0; k < 6; ++k) acc = fmaf(fcin[k], fcw1[k*48 + tid], acc);
        hfc[tid] = fmaxf(acc, 0.f);
    }
    __syncthreads();
    if (tid < 5) {
        float acc = fcb2[tid];
        #pragma unroll
        for (int k = 0; k < 48; ++k) acc = fmaf(hfc[k], fcw2[k*5 + tid], acc);
        logits[tid] = acc;
    }
    __syncthreads();
    if (tid == 0) {
        float m = logits[0];
        #pragma unroll
        for (int c = 1; c < 5; ++c) m = fmaxf(m, logits[c]);
        float ex[5], sum = 0.f;
        #pragma unroll
        for (int c = 0; c < 5; ++c) { ex[c] = __expf(logits[c] - m); sum += ex[c]; }
        float inv = 1.f / sum;
        #pragma unroll
        for (int c = 0; c < 5; ++c) out[(size_t)b * 5 + c] = ex[c] * inv;
    }
}

extern "C" void kernel_launch(void* const* d_in, const int* in_sizes, int n_in,
                              void* d_out, int out_size, void* d_ws, size_t ws_size,
                              hipStream_t stream) {
    const float* x     = (const float*)d_in[0];
    const float* bn_g  = (const float*)d_in[1];
    const float* bn_b  = (const float*)d_in[2];
    const float* bn_m  = (const float*)d_in[3];
    const float* bn_v  = (const float*)d_in[4];
    const float* frw1  = (const float*)d_in[5];
    const float* frb1  = (const float*)d_in[6];
    const float* frw2  = (const float*)d_in[7];
    const float* frb2  = (const float*)d_in[8];
    const float* frw3  = (const float*)d_in[9];
    const float* frb3  = (const float*)d_in[10];
    const float* fow1  = (const float*)d_in[11];
    const float* fob1  = (const float*)d_in[12];
    const float* fow2  = (const float*)d_in[13];
    const float* fob2  = (const float*)d_in[14];
    const float* fow3  = (const float*)d_in[15];
    const float* fob3  = (const float*)d_in[16];
    const float* fcw1  = (const float*)d_in[17];
    const float* fcb1  = (const float*)d_in[18];
    const float* fcw2  = (const float*)d_in[19];
    const float* fcb2  = (const float*)d_in[20];

    const int B = in_sizes[0] / (NCONST * NF);   // 512

    convint_fused<<<dim3(B), dim3(BLK), 0, stream>>>(
        x, bn_g, bn_b, bn_m, bn_v,
        frw1, frb1, frw2, frb2, frw3, frb3,
        fow1, fob1, fow2, fob2, fow3, fob3,
        fcw1, fcb1, fcw2, fcb2,
        (float*)d_out);
}